// Round 2
// baseline (88.479 us; speedup 1.0000x reference)
//
#include <hip/hip_runtime.h>

// ElementalGTOLogNormalSkinCutoff on MI355X (gfx950) — round 7
//
// Round-7 vs round-6 (r6 was neutral: phase-1 atomics were not the cost):
//  * TPA=10: each phase-2 thread owns TWO gaussians (g0, g0+10). One
//    ds_read_b128+ds_read_b64 per neighbour now feeds 2 exp2 chains ->
//    phase-2 LDS instruction count (the largest modeled pipe, ~10us/CU)
//    is halved. Accumulators split into TA/TB, all statically indexed.
//  * APB=32 (block still 320 threads), grid 512 blocks.
//  * Phase 0 stages the batch's coords (1.5 KB) and species codes (512 B)
//    into LDS; phase-1 per-neighbour gathers become LDS scatter reads
//    (~2 lanes/bank = free) instead of per-lane global gathers through
//    the TA port (~8us/CU modeled).
//  * Dropped __launch_bounds__ min-waves=5 (spill risk, proven no-help).
//
// Round-5 NaN fix retained: clamp amp to 1e-30 before log2 (boundary
// neighbours at d ~= 6.0 can give tiny-negative cut under rsqrt error).

#define B_   128
#define N_   128
#define M_   64
#define NG_  20
#define NSP_ 4
#define FPSIZE_ 600
#define APB  32                       // atoms per block (divides N_)
#define TPA  10                       // threads per atom (2 gaussians each)
#define BLOCK_THREADS (APB * TPA)     // 320 = 5 waves
#define NWAVE (BLOCK_THREADS / 64)    // 5
#define P1ITER ((APB + NWAVE - 1) / NWAVE)   // 7 wave-rounds cover 32 atoms

__global__ __launch_bounds__(BLOCK_THREADS)
void gto_fp_kernel(const float* __restrict__ coords,   // [B,N,3]
                   const int*   __restrict__ charges,  // [B,N]
                   const int*   __restrict__ counts,   // [B]
                   const int*   __restrict__ neigh,    // [B,N,M]
                   float*       __restrict__ out)      // [B,N,600]
{
    __shared__ float4 sP[APB][M_ + 1];      // c0, c1, c2, ux  (padded row)
    __shared__ float2 sQ[APB][M_ + 1];      // uy, uz          (padded row)
    __shared__ float  sC[3 * N_];           // batch coords, 1536 B
    __shared__ int    sZ[N_];               // species code per atom, 512 B
    __shared__ int    s_seg[APB][NSP_ + 1]; // species segment starts, [4]=total

    const int tid  = threadIdx.x;
    const int lane = tid & 63;
    const int wid  = tid >> 6;
    const int blockBase = blockIdx.x * APB;       // global atom base
    const int bidx      = blockBase / N_;         // uniform: APB divides N_
    const int alocBase  = blockBase - bidx * N_;  // in-batch atom base

    // ---------------- phase 0: stage coords + species (coalesced) --------
    for (int i = tid; i < 3 * N_; i += BLOCK_THREADS)
        sC[i] = coords[bidx * 3 * N_ + i];
    for (int i = tid; i < N_; i += BLOCK_THREADS) {
        const int z = charges[bidx * N_ + i];
        sZ[i] = (z == 1) ? 0 : (z - 5);   // {1,6,7,8} -> {0,1,2,3}
    }
    __syncthreads();

    // ---------------- phase 1: one wave == one atom's 64 slots -----------
#pragma unroll
    for (int it = 0; it < P1ITER; ++it) {
        const int la = wid + it * NWAVE;          // covers 0..31 (+ skips)
        if (la < APB) {
            const int atom = blockBase + la;
            const int aloc = alocBase + la;
            const int nb = neigh[atom * M_ + lane];
            bool v = (nb >= 0);
            int s = 0;
            float4 P = make_float4(0.f, 0.f, 0.f, 0.f);
            float2 Q = make_float2(0.f, 0.f);
            if (v) {
                // own-atom coords: wave-uniform LDS broadcast (free)
                const float ax = sC[aloc * 3 + 0];
                const float ay = sC[aloc * 3 + 1];
                const float az = sC[aloc * 3 + 2];
                // neighbour coords: LDS scatter (~2 lanes/bank avg)
                const float dx = ax - sC[nb * 3 + 0];
                const float dy = ay - sC[nb * 3 + 1];
                const float dz = az - sC[nb * 3 + 2];
                s = sZ[nb];

                const float d2     = dx * dx + dy * dy + dz * dz;
                const float inv_d  = __builtin_amdgcn_rsqf(d2);
                const float d      = d2 * inv_d;
                const float inv_d2 = inv_d * inv_d;

                const float dsw  = (d - 1.0f) * 0.2f;
                const float dsw2 = dsw * dsw;
                const float cut  = 1.0f - dsw2 * dsw * fmaf(6.0f, dsw2, fmaf(-15.0f, dsw, 10.0f));

                const float sigma2 = __logf(fmaf(2.0f, inv_d2, 1.0f));     // log(1+W/d^2)
                const float mu     = 0.5f * (__logf(d2) - sigma2);         // log(d)-s2/2
                const float amp    = fmaxf(__builtin_amdgcn_rsqf(sigma2) * cut * inv_d2,
                                           1.0e-30f);   // clamp: cut can be ~-1e-7 at d~6

                const float F  = -0.72134752f * __builtin_amdgcn_rcpf(sigma2); // -0.5*log2e/s2
                const float Fm = F * mu;
                const float c0 = F;
                const float c1 = -(Fm + Fm);
                const float c2 = fmaf(Fm, mu, __log2f(amp));

                P = make_float4(c0, c1, c2, dx * inv_d);
                Q = make_float2(dy * inv_d, dz * inv_d);
            }
            // wave-wide species bucketing: ballot + exclusive lane scan
            const unsigned long long b0 = __ballot(v && (s == 0));
            const unsigned long long b1 = __ballot(v && (s == 1));
            const unsigned long long b2 = __ballot(v && (s == 2));
            const unsigned long long b3 = __ballot(v && (s == 3));
            const int c0n = __popcll(b0), c1n = __popcll(b1),
                      c2n = __popcll(b2), c3n = __popcll(b3);
            const int o0 = __builtin_amdgcn_mbcnt_hi((unsigned)(b0 >> 32),
                           __builtin_amdgcn_mbcnt_lo((unsigned)b0, 0u));
            const int o1 = __builtin_amdgcn_mbcnt_hi((unsigned)(b1 >> 32),
                           __builtin_amdgcn_mbcnt_lo((unsigned)b1, 0u));
            const int o2 = __builtin_amdgcn_mbcnt_hi((unsigned)(b2 >> 32),
                           __builtin_amdgcn_mbcnt_lo((unsigned)b2, 0u));
            const int o3 = __builtin_amdgcn_mbcnt_hi((unsigned)(b3 >> 32),
                           __builtin_amdgcn_mbcnt_lo((unsigned)b3, 0u));
            int slot = o0;
            slot = (s == 1) ? c0n + o1 : slot;
            slot = (s == 2) ? c0n + c1n + o2 : slot;
            slot = (s == 3) ? c0n + c1n + c2n + o3 : slot;
            if (v) {
                sP[la][slot] = P;
                sQ[la][slot] = Q;
            }
            if (lane == 0) {
                s_seg[la][0] = 0;
                s_seg[la][1] = c0n;
                s_seg[la][2] = c0n + c1n;
                s_seg[la][3] = c0n + c1n + c2n;
                s_seg[la][4] = c0n + c1n + c2n + c3n;
            }
        }
    }
    __syncthreads();

    // ---------------- phase 2: accumulate TA/TB (2 gaussians/thread) -----
    const int g0 = tid % TPA;             // gaussian A = g0, B = g0 + 10
    const int la = tid / TPA;
    const int atom = blockBase + la;
    const int aloc = alocBase + la;

    const float offA = 0.3f * (float)(g0 + 1);
    const float offB = 0.3f * (float)(g0 + 11);
    const float loA = __logf(offA), loA2 = loA * loA;
    const float loB = __logf(offB), loB2 = loB * loB;

    float TA[NSP_][10], TB[NSP_][10];
#pragma unroll
    for (int s = 0; s < NSP_; ++s)
#pragma unroll
        for (int a = 0; a < 10; ++a) { TA[s][a] = 0.0f; TB[s][a] = 0.0f; }

#define BODY(SS, P, Q)                                                        \
    {                                                                         \
        const float radA = __builtin_amdgcn_exp2f(                            \
            fmaf(P.x, loA2, fmaf(P.y, loA, P.z)));                            \
        const float radB = __builtin_amdgcn_exp2f(                            \
            fmaf(P.x, loB2, fmaf(P.y, loB, P.z)));                            \
        const float rxA = radA * P.w, ryA = radA * Q.x, rzA = radA * Q.y;     \
        const float rxB = radB * P.w, ryB = radB * Q.x, rzB = radB * Q.y;     \
        TA[SS][0] += radA;                 TB[SS][0] += radB;                 \
        TA[SS][1] += rxA;                  TB[SS][1] += rxB;                  \
        TA[SS][2] += ryA;                  TB[SS][2] += ryB;                  \
        TA[SS][3] += rzA;                  TB[SS][3] += rzB;                  \
        TA[SS][4] = fmaf(rxA, P.w, TA[SS][4]);                                \
        TA[SS][5] = fmaf(rxA, Q.x, TA[SS][5]);                                \
        TA[SS][6] = fmaf(ryA, Q.x, TA[SS][6]);                                \
        TA[SS][7] = fmaf(rxA, Q.y, TA[SS][7]);                                \
        TA[SS][8] = fmaf(ryA, Q.y, TA[SS][8]);                                \
        TA[SS][9] = fmaf(rzA, Q.y, TA[SS][9]);                                \
        TB[SS][4] = fmaf(rxB, P.w, TB[SS][4]);                                \
        TB[SS][5] = fmaf(rxB, Q.x, TB[SS][5]);                                \
        TB[SS][6] = fmaf(ryB, Q.x, TB[SS][6]);                                \
        TB[SS][7] = fmaf(rxB, Q.y, TB[SS][7]);                                \
        TB[SS][8] = fmaf(ryB, Q.y, TB[SS][8]);                                \
        TB[SS][9] = fmaf(rzB, Q.y, TB[SS][9]);                                \
    }

#define ACC(SS)                                                               \
    {                                                                         \
        const int e0 = s_seg[la][SS];                                         \
        const int e1 = s_seg[la][SS + 1];                                     \
        int m = e0;                                                           \
        for (; m + 1 < e1; m += 2) {                                          \
            const float4 Pa = sP[la][m];     const float2 Qa = sQ[la][m];     \
            const float4 Pb = sP[la][m + 1]; const float2 Qb = sQ[la][m + 1]; \
            BODY(SS, Pa, Qa)                                                  \
            BODY(SS, Pb, Qb)                                                  \
        }                                                                     \
        if (m < e1) {                                                         \
            const float4 Pa = sP[la][m]; const float2 Qa = sQ[la][m];         \
            BODY(SS, Pa, Qa)                                                  \
        }                                                                     \
    }
    ACC(0) ACC(1) ACC(2) ACC(3)
#undef ACC
#undef BODY

    // ---------------- epilogue: two gaussians per thread ------------------
    const float amask = (aloc < counts[bidx]) ? 1.0f : 0.0f;

    // angw = [1, 1,1,1, 1,2,1,2,2,1]; lw = 1 for all l
    auto epilogue = [&](const float (&T)[NSP_][10], const int g, const float off) {
        const float iosp  = 1.0f / (off * 1.7724538509055159f);
        const float scale = amask * iosp * iosp;
        float* op = out + atom * FPSIZE_ + g;
#pragma unroll
        for (int l = 0; l < 3; ++l) {
            const int a0 = (l == 0) ? 0 : (l == 1) ? 1 : 4;
            const int a1 = (l == 0) ? 1 : (l == 1) ? 4 : 10;
#pragma unroll
            for (int s = 0; s < NSP_; ++s) {
                float v = 0.0f;
#pragma unroll
                for (int a = a0; a < a1; ++a) {
                    const float w = (a == 5 || a == 7 || a == 8) ? 2.0f : 1.0f;
                    v = fmaf(w * T[s][a], T[s][a], v);
                }
                op[(l * 10 + s) * NG_] = scale * v;
            }
            int mb = 4;
#pragma unroll
            for (int i = 0; i < NSP_; ++i) {
#pragma unroll
                for (int j = i + 1; j < NSP_; ++j) {
                    float v = 0.0f;
#pragma unroll
                    for (int a = a0; a < a1; ++a) {
                        const float w = (a == 5 || a == 7 || a == 8) ? 2.0f : 1.0f;
                        v = fmaf(w * T[i][a], T[j][a], v);
                    }
                    op[(l * 10 + mb) * NG_] = scale * (2.0f * v);
                    ++mb;
                }
            }
        }
    };
    epilogue(TA, g0, offA);
    epilogue(TB, g0 + 10, offB);
}

extern "C" void kernel_launch(void* const* d_in, const int* in_sizes, int n_in,
                              void* d_out, int out_size, void* d_ws, size_t ws_size,
                              hipStream_t stream) {
    const float* coords  = (const float*)d_in[0];
    const int*   charges = (const int*)d_in[1];
    const int*   counts  = (const int*)d_in[2];
    const int*   neigh   = (const int*)d_in[3];
    float*       outp    = (float*)d_out;

    const int blocks = (B_ * N_) / APB;   // 512
    gto_fp_kernel<<<blocks, BLOCK_THREADS, 0, stream>>>(coords, charges, counts, neigh, outp);
}

// Round 3
// 85.464 us; speedup vs baseline: 1.0353x; 1.0353x over previous
//
#include <hip/hip_runtime.h>

// ElementalGTOLogNormalSkinCutoff on MI355X (gfx950) — round 8
//
// Round-8 vs round-7 (r6/r7 both slightly regressed vs the r5 shape):
//  * Geometry restored to the empirically-best r5 shape: APB=16, TPA=20
//    (320 threads, 27 KB LDS, ~4-5 blocks/CU). No min-waves bound.
//  * Kept from r7: LDS-staged batch coords + species codes (phase 0),
//    ballot+mbcnt species bucketing (no LDS atomics).
//  * NEW: ACC inner loop unrolled x4 -> 4 independent ds_read->exp2->fma
//    chains per thread (latency theory: kernel is latency-bound, not
//    throughput-bound — halving LDS/gather traffic in r6/r7 was neutral).
//  * NEW: epilogue pairs adjacent g lanes via __shfl_xor(v,1) so even
//    lanes write float2: 30 scattered dword stores/thread -> 15 dwordx2
//    with 80B-contiguous segments (tail-heavy TA address work halved).
//
// Round-5 NaN fix retained: clamp amp to 1e-30 before log2.

#define B_   128
#define N_   128
#define M_   64
#define NG_  20
#define NSP_ 4
#define FPSIZE_ 600
#define APB  16                       // atoms per block (divides N_)
#define TPA  20                       // threads per atom (1 gaussian each)
#define BLOCK_THREADS (APB * TPA)     // 320 = 5 waves
#define NWAVE (BLOCK_THREADS / 64)    // 5
#define P1ITER ((APB + NWAVE - 1) / NWAVE)   // 4 wave-rounds cover 16 atoms

__global__ __launch_bounds__(BLOCK_THREADS)
void gto_fp_kernel(const float* __restrict__ coords,   // [B,N,3]
                   const int*   __restrict__ charges,  // [B,N]
                   const int*   __restrict__ counts,   // [B]
                   const int*   __restrict__ neigh,    // [B,N,M]
                   float*       __restrict__ out)      // [B,N,600]
{
    __shared__ float4 sP[APB][M_ + 1];      // c0, c1, c2, ux  (padded row)
    __shared__ float2 sQ[APB][M_ + 1];      // uy, uz          (padded row)
    __shared__ float  sC[3 * N_];           // batch coords, 1536 B
    __shared__ int    sZ[N_];               // species code per atom, 512 B
    __shared__ int    s_seg[APB][NSP_ + 1]; // species segment starts, [4]=total

    const int tid  = threadIdx.x;
    const int lane = tid & 63;
    const int wid  = tid >> 6;
    const int blockBase = blockIdx.x * APB;       // global atom base
    const int bidx      = blockBase / N_;         // uniform: APB divides N_
    const int alocBase  = blockBase - bidx * N_;  // in-batch atom base

    // ---------------- phase 0: stage coords + species (coalesced) --------
    for (int i = tid; i < 3 * N_; i += BLOCK_THREADS)
        sC[i] = coords[bidx * 3 * N_ + i];
    for (int i = tid; i < N_; i += BLOCK_THREADS) {
        const int z = charges[bidx * N_ + i];
        sZ[i] = (z == 1) ? 0 : (z - 5);   // {1,6,7,8} -> {0,1,2,3}
    }
    __syncthreads();

    // ---------------- phase 1: one wave == one atom's 64 slots -----------
#pragma unroll
    for (int it = 0; it < P1ITER; ++it) {
        const int la = wid + it * NWAVE;          // wave-uniform
        if (la < APB) {
            const int atom = blockBase + la;
            const int aloc = alocBase + la;
            const int nb = neigh[atom * M_ + lane];
            bool v = (nb >= 0);
            int s = 0;
            float4 P = make_float4(0.f, 0.f, 0.f, 0.f);
            float2 Q = make_float2(0.f, 0.f);
            if (v) {
                const float ax = sC[aloc * 3 + 0];     // wave-uniform bcast
                const float ay = sC[aloc * 3 + 1];
                const float az = sC[aloc * 3 + 2];
                const float dx = ax - sC[nb * 3 + 0];  // LDS scatter (~free)
                const float dy = ay - sC[nb * 3 + 1];
                const float dz = az - sC[nb * 3 + 2];
                s = sZ[nb];

                const float d2     = dx * dx + dy * dy + dz * dz;
                const float inv_d  = __builtin_amdgcn_rsqf(d2);
                const float d      = d2 * inv_d;
                const float inv_d2 = inv_d * inv_d;

                const float dsw  = (d - 1.0f) * 0.2f;
                const float dsw2 = dsw * dsw;
                const float cut  = 1.0f - dsw2 * dsw * fmaf(6.0f, dsw2, fmaf(-15.0f, dsw, 10.0f));

                const float sigma2 = __logf(fmaf(2.0f, inv_d2, 1.0f));     // log(1+W/d^2)
                const float mu     = 0.5f * (__logf(d2) - sigma2);         // log(d)-s2/2
                const float amp    = fmaxf(__builtin_amdgcn_rsqf(sigma2) * cut * inv_d2,
                                           1.0e-30f);   // clamp: cut can be ~-1e-7 at d~6

                const float F  = -0.72134752f * __builtin_amdgcn_rcpf(sigma2); // -0.5*log2e/s2
                const float Fm = F * mu;
                const float c0 = F;
                const float c1 = -(Fm + Fm);
                const float c2 = fmaf(Fm, mu, __log2f(amp));

                P = make_float4(c0, c1, c2, dx * inv_d);
                Q = make_float2(dy * inv_d, dz * inv_d);
            }
            // wave-wide species bucketing: ballot + exclusive lane scan
            const unsigned long long b0 = __ballot(v && (s == 0));
            const unsigned long long b1 = __ballot(v && (s == 1));
            const unsigned long long b2 = __ballot(v && (s == 2));
            const unsigned long long b3 = __ballot(v && (s == 3));
            const int c0n = __popcll(b0), c1n = __popcll(b1),
                      c2n = __popcll(b2), c3n = __popcll(b3);
            const int o0 = __builtin_amdgcn_mbcnt_hi((unsigned)(b0 >> 32),
                           __builtin_amdgcn_mbcnt_lo((unsigned)b0, 0u));
            const int o1 = __builtin_amdgcn_mbcnt_hi((unsigned)(b1 >> 32),
                           __builtin_amdgcn_mbcnt_lo((unsigned)b1, 0u));
            const int o2 = __builtin_amdgcn_mbcnt_hi((unsigned)(b2 >> 32),
                           __builtin_amdgcn_mbcnt_lo((unsigned)b2, 0u));
            const int o3 = __builtin_amdgcn_mbcnt_hi((unsigned)(b3 >> 32),
                           __builtin_amdgcn_mbcnt_lo((unsigned)b3, 0u));
            int slot = o0;
            slot = (s == 1) ? c0n + o1 : slot;
            slot = (s == 2) ? c0n + c1n + o2 : slot;
            slot = (s == 3) ? c0n + c1n + c2n + o3 : slot;
            if (v) {
                sP[la][slot] = P;
                sQ[la][slot] = Q;
            }
            if (lane == 0) {
                s_seg[la][0] = 0;
                s_seg[la][1] = c0n;
                s_seg[la][2] = c0n + c1n;
                s_seg[la][3] = c0n + c1n + c2n;
                s_seg[la][4] = c0n + c1n + c2n + c3n;
            }
        }
    }
    __syncthreads();

    // ---------------- phase 2: accumulate T (ILP-4) -----------------------
    const int g  = tid % TPA;
    const int la = tid / TPA;
    const int atom = blockBase + la;
    const int aloc = alocBase + la;

    const float off = 0.3f * (float)(g + 1);
    const float lo  = __logf(off);            // natural-log space
    const float lo2 = lo * lo;

    float T[NSP_][10];
#pragma unroll
    for (int s = 0; s < NSP_; ++s)
#pragma unroll
        for (int a = 0; a < 10; ++a) T[s][a] = 0.0f;

#define BODY(SS, P, Q)                                                        \
    {                                                                         \
        const float rad = __builtin_amdgcn_exp2f(                             \
            fmaf(P.x, lo2, fmaf(P.y, lo, P.z)));                              \
        const float rx = rad * P.w, ry = rad * Q.x, rz = rad * Q.y;           \
        T[SS][0] += rad;                                                      \
        T[SS][1] += rx;  T[SS][2] += ry;  T[SS][3] += rz;                     \
        T[SS][4] = fmaf(rx, P.w, T[SS][4]);                                   \
        T[SS][5] = fmaf(rx, Q.x, T[SS][5]);                                   \
        T[SS][6] = fmaf(ry, Q.x, T[SS][6]);                                   \
        T[SS][7] = fmaf(rx, Q.y, T[SS][7]);                                   \
        T[SS][8] = fmaf(ry, Q.y, T[SS][8]);                                   \
        T[SS][9] = fmaf(rz, Q.y, T[SS][9]);                                   \
    }

#define ACC(SS)                                                               \
    {                                                                         \
        const int e0 = s_seg[la][SS];                                         \
        const int e1 = s_seg[la][SS + 1];                                     \
        int m = e0;                                                           \
        for (; m + 3 < e1; m += 4) {                                          \
            const float4 Pa = sP[la][m];     const float2 Qa = sQ[la][m];     \
            const float4 Pb = sP[la][m + 1]; const float2 Qb = sQ[la][m + 1]; \
            const float4 Pc = sP[la][m + 2]; const float2 Qc = sQ[la][m + 2]; \
            const float4 Pd = sP[la][m + 3]; const float2 Qd = sQ[la][m + 3]; \
            BODY(SS, Pa, Qa)                                                  \
            BODY(SS, Pb, Qb)                                                  \
            BODY(SS, Pc, Qc)                                                  \
            BODY(SS, Pd, Qd)                                                  \
        }                                                                     \
        if (m + 1 < e1) {                                                     \
            const float4 Pa = sP[la][m];     const float2 Qa = sQ[la][m];     \
            const float4 Pb = sP[la][m + 1]; const float2 Qb = sQ[la][m + 1]; \
            BODY(SS, Pa, Qa)                                                  \
            BODY(SS, Pb, Qb)                                                  \
            m += 2;                                                           \
        }                                                                     \
        if (m < e1) {                                                         \
            const float4 Pa = sP[la][m]; const float2 Qa = sQ[la][m];         \
            BODY(SS, Pa, Qa)                                                  \
        }                                                                     \
    }
    ACC(0) ACC(1) ACC(2) ACC(3)
#undef ACC
#undef BODY

    // ---------------- epilogue: paired float2 stores ----------------------
    // lane parity == g parity (TPA even), so lanes (g even, g odd) of the
    // same atom pair up; even lane stores {v_even, v_odd} as float2.
    const float amask = (aloc < counts[bidx]) ? 1.0f : 0.0f;
    const float iosp  = 1.0f / (off * 1.7724538509055159f);
    const float scale = amask * iosp * iosp;
    const bool  geven = ((g & 1) == 0);
    float* op = out + atom * FPSIZE_ + g;

#define EMIT(CH, V)                                                           \
    {                                                                         \
        const float _v  = (V);                                                \
        const float _vp = __shfl_xor(_v, 1);                                  \
        if (geven) *(float2*)(op + (CH) * NG_) = make_float2(_v, _vp);        \
    }

    // angw = [1, 1,1,1, 1,2,1,2,2,1]; lw = 1 for all l
#pragma unroll
    for (int l = 0; l < 3; ++l) {
        const int a0 = (l == 0) ? 0 : (l == 1) ? 1 : 4;
        const int a1 = (l == 0) ? 1 : (l == 1) ? 4 : 10;
#pragma unroll
        for (int s = 0; s < NSP_; ++s) {
            float v = 0.0f;
#pragma unroll
            for (int a = a0; a < a1; ++a) {
                const float w = (a == 5 || a == 7 || a == 8) ? 2.0f : 1.0f;
                v = fmaf(w * T[s][a], T[s][a], v);
            }
            EMIT(l * 10 + s, scale * v)
        }
        int mb = 4;
#pragma unroll
        for (int i = 0; i < NSP_; ++i) {
#pragma unroll
            for (int j = i + 1; j < NSP_; ++j) {
                float v = 0.0f;
#pragma unroll
                for (int a = a0; a < a1; ++a) {
                    const float w = (a == 5 || a == 7 || a == 8) ? 2.0f : 1.0f;
                    v = fmaf(w * T[i][a], T[j][a], v);
                }
                EMIT(l * 10 + mb, scale * (2.0f * v))
                ++mb;
            }
        }
    }
#undef EMIT
}

extern "C" void kernel_launch(void* const* d_in, const int* in_sizes, int n_in,
                              void* d_out, int out_size, void* d_ws, size_t ws_size,
                              hipStream_t stream) {
    const float* coords  = (const float*)d_in[0];
    const int*   charges = (const int*)d_in[1];
    const int*   counts  = (const int*)d_in[2];
    const int*   neigh   = (const int*)d_in[3];
    float*       outp    = (float*)d_out;

    const int blocks = (B_ * N_) / APB;   // 1024
    gto_fp_kernel<<<blocks, BLOCK_THREADS, 0, stream>>>(coords, charges, counts, neigh, outp);
}